// Round 3
// baseline (811.936 us; speedup 1.0000x reference)
//
#include <hip/hip_runtime.h>

typedef __bf16 bf16_t;
typedef __bf16 bf16x8 __attribute__((ext_vector_type(8)));
typedef __bf16 bf16x4 __attribute__((ext_vector_type(4)));
typedef float  f32x4  __attribute__((ext_vector_type(4)));

#define NB 16   // B
#define NN 30   // N
#define NT 50   // T
#define ND 4    // D
#define NK 4    // K experts
#define NE 870  // E = N*(N-1)

// canonical bf16 workspace layout (element offsets from ws+16)
#define C_INPUTS   0
#define C_RELTYPE  96000
#define C_W1       151680
#define C_B1       155776
#define C_W2       156288
#define C_B2       221824
#define C_OW1      222336
#define C_OB1      239232
#define C_OW2      239360
#define C_OB2      255744
#define C_OW3      255872
#define C_OB3      256384
#define AGG_BYTE_OFF (1u << 20)   // aggbuf (fp32) at ws + 1MB

__device__ __forceinline__ bf16x8 bzero8() {
  bf16x8 z;
#pragma unroll
  for (int j = 0; j < 8; ++j) z[j] = (bf16_t)0.0f;
  return z;
}

__device__ __forceinline__ f32x4 make4(float a, float b, float c, float d) {
  f32x4 v; v[0] = a; v[1] = b; v[2] = c; v[3] = d; return v;
}

// relu + cvt to bf16 + packed 8B store (4 consecutive columns)
__device__ __forceinline__ void pack_store4(bf16_t* dst, f32x4 a) {
  bf16x4 v;
  v[0] = (bf16_t)fmaxf(a[0], 0.0f);
  v[1] = (bf16_t)fmaxf(a[1], 0.0f);
  v[2] = (bf16_t)fmaxf(a[2], 0.0f);
  v[3] = (bf16_t)fmaxf(a[3], 0.0f);
  *(bf16x4*)dst = v;
}

// ---------------------------------------------------------------------------
// dtype detection + canonicalization to bf16.
// Even 16-bit words of a bf16 array are whole bf16 samples (sane exponent);
// even words of an fp32 array are mantissa low-halves (random exponent).
// ---------------------------------------------------------------------------
__device__ __forceinline__ int detect_isbf16(const void* p) {
  const unsigned short* w = (const unsigned short*)p;
  int c = 0;
#pragma unroll 4
  for (int i = 0; i < 256; i += 2) {
    const int e = (w[i] >> 7) & 0xFF;
    if (e >= 100 && e <= 150) ++c;
  }
  return c >= 96;   // bf16 ~128/128, fp32 ~25/128
}

__device__ __forceinline__ void conv_arr(const void* src, bf16_t* dst, int n,
                                         int isbf, int gtid, int gsz) {
  if (isbf) {
    const unsigned short* s = (const unsigned short*)src;
    unsigned short* d = (unsigned short*)dst;
    for (int i = gtid; i < n; i += gsz) d[i] = s[i];
  } else {
    const float* s = (const float*)src;
    for (int i = gtid; i < n; i += gsz) dst[i] = (bf16_t)s[i];
  }
}

__global__ void convert_kernel(const void* inputs, const void* rel_type,
                               const void* W1, const void* b1,
                               const void* W2, const void* b2,
                               const void* oW1, const void* ob1,
                               const void* oW2, const void* ob2,
                               const void* oW3, const void* ob3,
                               void* ws)
{
  __shared__ int sflag;
  if (threadIdx.x == 0) sflag = detect_isbf16(inputs);
  __syncthreads();
  const int isbf = sflag;
  if (blockIdx.x == 0 && threadIdx.x == 0) *(int*)ws = isbf;
  bf16_t* cb = (bf16_t*)((char*)ws + 16);
  const int gtid = blockIdx.x * blockDim.x + threadIdx.x;
  const int gsz  = gridDim.x * blockDim.x;
  conv_arr(inputs,   cb + C_INPUTS,  96000, isbf, gtid, gsz);
  conv_arr(rel_type, cb + C_RELTYPE, 55680, isbf, gtid, gsz);
  conv_arr(W1,  cb + C_W1,  4096,  isbf, gtid, gsz);
  conv_arr(b1,  cb + C_B1,  512,   isbf, gtid, gsz);
  conv_arr(W2,  cb + C_W2,  65536, isbf, gtid, gsz);
  conv_arr(b2,  cb + C_B2,  512,   isbf, gtid, gsz);
  conv_arr(oW1, cb + C_OW1, 16896, isbf, gtid, gsz);
  conv_arr(ob1, cb + C_OB1, 128,   isbf, gtid, gsz);
  conv_arr(oW2, cb + C_OW2, 16384, isbf, gtid, gsz);
  conv_arr(ob2, cb + C_OB2, 128,   isbf, gtid, gsz);
  conv_arr(oW3, cb + C_OW3, 512,   isbf, gtid, gsz);
  conv_arr(ob3, cb + C_OB3, 4,     isbf, gtid, gsz);
}

// ---------------------------------------------------------------------------
// Edge kernel: per (b,t,half) block computes 15 receiver nodes (435 edges),
// all 4 experts, and writes agg rows (block-exclusive -> plain stores).
// ---------------------------------------------------------------------------
struct EdgeSmem {
  union {
    bf16_t w2t[128 * 136];   // staged W2[k]^T : [m][kk], stride 136
    bf16_t h[64 * 136];      // layer-1 activations [edge][n], stride 136
  } u;                       // 34816 B
  float  agg[16 * 128];      // 8192 B  (row 15 = scratch for the 1-node tile)
  float  rt4[436 * 4];       // 6976 B  rel_type slice, [edge_local][k]
  bf16_t w1t[128 * 8];       // 2048 B  W1[k]^T : [n][j]
  float  b1f4[512];          // 2048 B  b1 all k
  float  b2f4[512];          // 2048 B  b2 all k
  bf16_t xl[128];            // 256 B   x[b,t,:,:] (30 nodes x 4)
};                            // ~56.4 KB -> 2 blocks/CU

__global__ __launch_bounds__(256, 2)
void edge_kernel(const bf16_t* __restrict__ inputs,
                 const bf16_t* __restrict__ rel_type,
                 const bf16_t* __restrict__ W1,
                 const bf16_t* __restrict__ b1,
                 const bf16_t* __restrict__ W2,
                 const bf16_t* __restrict__ b2,
                 float* __restrict__ aggbuf)
{
  __shared__ EdgeSmem s;
  const int tid  = threadIdx.x;
  const int bid  = blockIdx.x;
  const int nhalf = bid & 1;          // which 15-node half
  const int bt   = bid >> 1;          // b*T + t
  const int b    = bt / NT;
  const int t    = bt - b * NT;
  const int wave = tid >> 6;
  const int lane = tid & 63;
  const int quad = lane >> 4;
  const int lm   = lane & 15;
  const int rowm = wave * 16 + lm;    // this lane's edge-row within a tile

  // ---- one-time staging ----
  if (tid < 30) {
    *(uint2*)&s.xl[tid * 4] = *(const uint2*)&inputs[((b * NN + tid) * NT + t) * ND];
  }
  for (int i = tid; i < 512; i += 256) {
    s.b1f4[i] = (float)b1[i];
    s.b2f4[i] = (float)b2[i];
  }
  {
    const int e0g = b * NE + nhalf * 435;
    for (int i = tid; i < 435; i += 256) {
      union { uint2 u2; bf16_t h[4]; } c;
      c.u2 = *(const uint2*)&rel_type[(e0g + i) * NK];
#pragma unroll
      for (int kk = 0; kk < 4; ++kk) s.rt4[i * 4 + kk] = (float)c.h[kk];
    }
  }
  for (int i = tid; i < 16 * 128; i += 256) s.agg[i] = 0.0f;

  for (int k = 0; k < NK; ++k) {
    __syncthreads();   // protects union reuse + initial staging
    // ---- stage W2[k]^T and W1[k]^T ----
    {
      const uint4* src = (const uint4*)(W2 + k * (128 * 128));
      for (int i = tid; i < 2048; i += 256) {
        union { uint4 v; bf16_t h[8]; } c;
        c.v = src[i];
        const int base = i * 8;
        const int kk = base >> 7;
        const int n0 = base & 127;
#pragma unroll
        for (int j = 0; j < 8; ++j) s.u.w2t[(n0 + j) * 136 + kk] = c.h[j];
      }
      for (int i = tid; i < 1024; i += 256) {
        const int j = i >> 7, n = i & 127;
        s.w1t[n * 8 + j] = W1[k * 1024 + i];
      }
    }
    __syncthreads();

    // ---- hoist W2 B-fragments + biases into registers ----
    bf16x8 w2f[8][4];
    f32x4  b1v[8];
    float  b2s[8];
#pragma unroll
    for (int ct = 0; ct < 8; ++ct) {
      const int n = ct * 16 + lm;
#pragma unroll
      for (int kc = 0; kc < 4; ++kc)
        w2f[ct][kc] = *(const bf16x8*)&s.u.w2t[n * 136 + kc * 32 + quad * 8];
      const int nb = ct * 16 + quad * 4;
      b1v[ct] = make4(s.b1f4[k * 128 + nb],     s.b1f4[k * 128 + nb + 1],
                      s.b1f4[k * 128 + nb + 2], s.b1f4[k * 128 + nb + 3]);
      b2s[ct] = s.b2f4[k * 128 + ct * 16 + lm];
    }
    __syncthreads();   // hoists done before h overwrites the union

    // ---- 8 tiles of 2 nodes (58 edges, padded to 64); tile 7 has 1 node ----
    for (int tt = 0; tt < 8; ++tt) {
      const int vcnt = (tt < 7) ? 58 : 29;
      const int n0g  = nhalf * 15 + tt * 2;

      float rtv[4];
      bool  seg1[4];
#pragma unroll
      for (int r = 0; r < 4; ++r) {
        const int rr = wave * 16 + quad * 4 + r;
        rtv[r]  = (rr < vcnt) ? s.rt4[(tt * 58 + rr) * 4 + k] : 0.0f;
        seg1[r] = (rr >= 29);
      }

      // premsg B-fragment: [x_recv(4), x_send(4)] at k=0..7, zero elsewhere
      bf16x8 pm = bzero8();
      if (quad == 0 && rowm < vcnt) {
        const int recv = n0g + (rowm >= 29);
        const int jj   = rowm - ((rowm >= 29) ? 29 : 0);
        const int send = jj + ((jj >= recv) ? 1 : 0);
        union { uint2 u2[2]; bf16x8 v; } c;
        c.u2[0] = *(const uint2*)&s.xl[recv * 4];
        c.u2[1] = *(const uint2*)&s.xl[send * 4];
        pm = c.v;
      }

      // layer 1 (operand-swapped): D'[n][edge]; packed b64 stores to h[edge][n]
#pragma unroll
      for (int ct = 0; ct < 8; ++ct) {
        bf16x8 w1f;
        if (quad == 0) w1f = *(const bf16x8*)&s.w1t[(ct * 16 + lm) * 8];
        else           w1f = bzero8();
        f32x4 a1 = __builtin_amdgcn_mfma_f32_16x16x32_bf16(w1f, pm, b1v[ct], 0, 0, 0);
        pack_store4(&s.u.h[rowm * 136 + ct * 16 + quad * 4], a1);
      }

      // layer 2 (un-swapped): D[edge][m], bias in C-init
      f32x4 acc2[8];
#pragma unroll
      for (int ct = 0; ct < 8; ++ct)
        acc2[ct] = make4(b2s[ct], b2s[ct], b2s[ct], b2s[ct]);
#pragma unroll
      for (int kc = 0; kc < 4; ++kc) {
        const bf16x8 af = *(const bf16x8*)&s.u.h[rowm * 136 + kc * 32 + quad * 8];
#pragma unroll
        for (int ct = 0; ct < 8; ++ct)
          acc2[ct] = __builtin_amdgcn_mfma_f32_16x16x32_bf16(af, w2f[ct][kc], acc2[ct], 0, 0, 0);
      }

      // relu * rt, segmented reduce over 16 edges (4 regs + quad butterfly)
#pragma unroll
      for (int ct = 0; ct < 8; ++ct) {
        float p0 = 0.0f, p1 = 0.0f;
#pragma unroll
        for (int r = 0; r < 4; ++r) {
          const float v = fmaxf(acc2[ct][r], 0.0f) * rtv[r];
          p0 += seg1[r] ? 0.0f : v;
          p1 += seg1[r] ? v : 0.0f;
        }
        p0 += __shfl_xor(p0, 16, 64);
        p0 += __shfl_xor(p0, 32, 64);
        p1 += __shfl_xor(p1, 16, 64);
        p1 += __shfl_xor(p1, 32, 64);
        if (quad == 0) {
          const int col = ct * 16 + lm;
          atomicAdd(&s.agg[(tt * 2) * 128 + col], p0);
          atomicAdd(&s.agg[(tt * 2 + 1) * 128 + col], p1);
        }
      }
    }
  }

  __syncthreads();
  for (int i = tid; i < 15 * 128; i += 256) {
    const int r = i >> 7, c = i & 127;
    aggbuf[(size_t)(bt * NN + nhalf * 15 + r) * 128 + c] = s.agg[r * 128 + c];
  }
}

// ---------------------------------------------------------------------------
// Node kernel: 64 node-instances per block; aug = [x(4), agg(128), 0-pad]
// layers 132->128->128 via MFMA (swapped, packed stores), 128->4 via VALU.
// Output stored as bf16 or fp32 per the detected flag.
// ---------------------------------------------------------------------------
struct NodeSmem {
  union {
    bf16_t wt[128 * 136];    // oW1^T then oW2^T : [n][kk]
    bf16_t h2[64 * 136];
  } u;                       // 34816 B
  bf16_t h1[64 * 136];       // 17408 B
  bf16_t xres[64 * 4];       // 512 B
  float  b1f[128];
  float  b2f[128];
  float  w3f[128 * 4];
  float  b3f[4];
};                            // ~55.8 KB

__global__ __launch_bounds__(256, 2)
void node_kernel(const bf16_t* __restrict__ inputs,
                 const bf16_t* __restrict__ oW1, const bf16_t* __restrict__ ob1,
                 const bf16_t* __restrict__ oW2, const bf16_t* __restrict__ ob2,
                 const bf16_t* __restrict__ oW3, const bf16_t* __restrict__ ob3,
                 const int* __restrict__ flagptr,
                 const float* __restrict__ aggbuf,
                 void* __restrict__ outp)
{
  __shared__ NodeSmem s;
  const int tid  = threadIdx.x;
  const int wave = tid >> 6;
  const int lane = tid & 63;
  const int quad = lane >> 4;
  const int lm   = lane & 15;
  const int row  = wave * 16 + lm;
  const int r0   = blockIdx.x * 64;
  const int isbf = *flagptr;

  // ---- stage oW1^T (132x128), zero kk=132..135 ----
  for (int i = tid; i < 2112; i += 256) {
    union { uint4 v; bf16_t h[8]; } c;
    const int base = i * 8;
    c.v = *(const uint4*)(oW1 + base);
    const int kk = base >> 7;
    const int n0 = base & 127;
#pragma unroll
    for (int j = 0; j < 8; ++j) s.u.wt[(n0 + j) * 136 + kk] = c.h[j];
  }
  if (tid < 128) {
#pragma unroll
    for (int j = 0; j < 4; ++j) s.u.wt[tid * 136 + 132 + j] = (bf16_t)0.0f;
  }
  if (tid < 64) {
    const int r  = r0 + tid;
    const int n  = r % NN;
    const int bt = r / NN;
    const int t  = bt % NT;
    const int b  = bt / NT;
    *(uint2*)&s.xres[tid * 4] = *(const uint2*)&inputs[((b * NN + n) * NT + t) * ND];
  }
  if (tid < 128) s.b1f[tid] = (float)ob1[tid];
  else           s.b2f[tid - 128] = (float)ob2[tid - 128];
  if (tid < 4) s.b3f[tid] = (float)ob3[tid];
  for (int i = tid; i < 512; i += 256) s.w3f[i] = (float)oW3[i];
  __syncthreads();

  // ---- hoist oW1 fragments (5 K-chunks; chunk 4 real only for quad 0) ----
  bf16x8 wfrag[8][5];
#pragma unroll
  for (int ct = 0; ct < 8; ++ct) {
    const int n = ct * 16 + lm;
#pragma unroll
    for (int kc = 0; kc < 5; ++kc) {
      if (kc == 4 && quad != 0) wfrag[ct][kc] = bzero8();
      else wfrag[ct][kc] = *(const bf16x8*)&s.u.wt[n * 136 + kc * 32 + quad * 8];
    }
  }

  // ---- build aug B-fragments directly from global agg (fp32) + x ----
  bf16x8 bfa[5];
  {
    const float* aggrow = aggbuf + (size_t)(r0 + row) * 128;
    float tmp[8];
    if (quad == 0) {
#pragma unroll
      for (int j = 0; j < 4; ++j) tmp[j] = (float)s.xres[row * 4 + j];
      const float4 a = *(const float4*)(aggrow);
      tmp[4] = a.x; tmp[5] = a.y; tmp[6] = a.z; tmp[7] = a.w;
    } else {
      const int c0 = quad * 8 - 4;
      const float4 a = *(const float4*)(aggrow + c0);
      const float4 d = *(const float4*)(aggrow + c0 + 4);
      tmp[0] = a.x; tmp[1] = a.y; tmp[2] = a.z; tmp[3] = a.w;
      tmp[4] = d.x; tmp[5] = d.y; tmp[6] = d.z; tmp[7] = d.w;
    }
#pragma unroll
    for (int j = 0; j < 8; ++j) bfa[0][j] = (bf16_t)tmp[j];
#pragma unroll
    for (int kc = 1; kc < 4; ++kc) {
      const int c0 = kc * 32 + quad * 8 - 4;
      const float4 a = *(const float4*)(aggrow + c0);
      const float4 d = *(const float4*)(aggrow + c0 + 4);
      tmp[0] = a.x; tmp[1] = a.y; tmp[2] = a.z; tmp[3] = a.w;
      tmp[4] = d.x; tmp[5] = d.y; tmp[6] = d.z; tmp[7] = d.w;
#pragma unroll
      for (int j = 0; j < 8; ++j) bfa[kc][j] = (bf16_t)tmp[j];
    }
    if (quad == 0) {
      const float4 a = *(const float4*)(aggrow + 124);
      tmp[0] = a.x; tmp[1] = a.y; tmp[2] = a.z; tmp[3] = a.w;
      tmp[4] = 0.f; tmp[5] = 0.f; tmp[6] = 0.f; tmp[7] = 0.f;
#pragma unroll
      for (int j = 0; j < 8; ++j) bfa[4][j] = (bf16_t)tmp[j];
    } else bfa[4] = bzero8();
  }

  // ---- layer 1 (swapped): h1[row][n] ----
  {
    f32x4 acc[8];
#pragma unroll
    for (int ct = 0; ct < 8; ++ct) {
      const int nb = ct * 16 + quad * 4;
      acc[ct] = make4(s.b1f[nb], s.b1f[nb + 1], s.b1f[nb + 2], s.b1f[nb + 3]);
    }
#pragma unroll
    for (int kc = 0; kc < 5; ++kc) {
#pragma unroll
      for (int ct = 0; ct < 8; ++ct)
        acc[ct] = __builtin_amdgcn_mfma_f32_16x16x32_bf16(wfrag[ct][kc], bfa[kc], acc[ct], 0, 0, 0);
    }
#pragma unroll
    for (int ct = 0; ct < 8; ++ct)
      pack_store4(&s.h1[row * 136 + ct * 16 + quad * 4], acc[ct]);
  }
  __syncthreads();

  // ---- stage oW2^T ----
  for (int i = tid; i < 2048; i += 256) {
    union { uint4 v; bf16_t h[8]; } c;
    const int base = i * 8;
    c.v = *(const uint4*)(oW2 + base);
    const int kk = base >> 7;
    const int n0 = base & 127;
#pragma unroll
    for (int j = 0; j < 8; ++j) s.u.wt[(n0 + j) * 136 + kk] = c.h[j];
  }
  __syncthreads();

  // ---- hoist oW2 fragments ----
#pragma unroll
  for (int ct = 0; ct < 8; ++ct) {
    const int n = ct * 16 + lm;
#pragma unroll
    for (int kc = 0; kc < 4; ++kc)
      wfrag[ct][kc] = *(const bf16x8*)&s.u.wt[n * 136 + kc * 32 + quad * 8];
  }
  __syncthreads();   // all hoists done before h2 overwrites wt

  // ---- layer 2 (swapped): h2[row][m] ----
  {
    f32x4 acc[8];
#pragma unroll
    for (int ct = 0; ct < 8; ++ct) {
      const int mb = ct * 16 + quad * 4;
      acc[ct] = make4(s.b2f[mb], s.b2f[mb + 1], s.b2f[mb + 2], s.b2f[mb + 3]);
    }
#pragma unroll
    for (int kc = 0; kc < 4; ++kc) {
      const bf16x8 af = *(const bf16x8*)&s.h1[row * 136 + kc * 32 + quad * 8];
#pragma unroll
      for (int ct = 0; ct < 8; ++ct)
        acc[ct] = __builtin_amdgcn_mfma_f32_16x16x32_bf16(wfrag[ct][kc], af, acc[ct], 0, 0, 0);
    }
#pragma unroll
    for (int ct = 0; ct < 8; ++ct)
      pack_store4(&s.u.h2[row * 136 + ct * 16 + quad * 4], acc[ct]);
  }

  // ---- layer 3 (VALU, wave-private rows) + residual + store ----
  {
    const int rloc = tid >> 2;
    const int d    = tid & 3;
    float a3 = s.b3f[d];
#pragma unroll
    for (int g = 0; g < 16; ++g) {
      const bf16x8 hv = *(const bf16x8*)&s.u.h2[rloc * 136 + g * 8];
#pragma unroll
      for (int j = 0; j < 8; ++j)
        a3 += (float)hv[j] * s.w3f[(g * 8 + j) * 4 + d];
    }
    a3 += (float)s.xres[rloc * 4 + d];
    const int r  = r0 + rloc;
    const int n  = r % NN;
    const int bt = r / NN;
    const int t  = bt % NT;
    const int b  = bt / NT;
    if (t < NT - 1) {
      const int oidx = ((b * NN + n) * (NT - 1) + t) * ND + d;
      if (isbf) ((bf16_t*)outp)[oidx] = (bf16_t)a3;
      else      ((float*)outp)[oidx]  = a3;
    }
  }
}

extern "C" void kernel_launch(void* const* d_in, const int* in_sizes, int n_in,
                              void* d_out, int out_size, void* d_ws, size_t ws_size,
                              hipStream_t stream) {
  // d_in[2] rel_rec, d_in[3] rel_send: fixed one-hot structure, computed
  // analytically. d_in[14] pred_steps == 1.
  char* ws = (char*)d_ws;
  bf16_t* cb = (bf16_t*)(ws + 16);            // canonical bf16 arrays
  float* aggbuf = (float*)(ws + AGG_BYTE_OFF); // 24000*128*4 B = 12.29 MB

  convert_kernel<<<dim3(256), dim3(256), 0, stream>>>(
      d_in[0], d_in[1], d_in[4], d_in[5], d_in[6], d_in[7],
      d_in[8], d_in[9], d_in[10], d_in[11], d_in[12], d_in[13], d_ws);

  edge_kernel<<<dim3(NB * NT * 2), dim3(256), 0, stream>>>(
      cb + C_INPUTS, cb + C_RELTYPE, cb + C_W1, cb + C_B1,
      cb + C_W2, cb + C_B2, aggbuf);

  node_kernel<<<dim3((NB * NT * NN) / 64), dim3(256), 0, stream>>>(
      cb + C_INPUTS, cb + C_OW1, cb + C_OB1, cb + C_OW2, cb + C_OB2,
      cb + C_OW3, cb + C_OB3, (const int*)d_ws, aggbuf, d_out);
}

// Round 4
// 697.010 us; speedup vs baseline: 1.1649x; 1.1649x over previous
//
#include <hip/hip_runtime.h>

typedef __bf16 bf16_t;
typedef __bf16 bf16x8 __attribute__((ext_vector_type(8)));
typedef __bf16 bf16x4 __attribute__((ext_vector_type(4)));
typedef float  f32x4  __attribute__((ext_vector_type(4)));

#define NB 16   // B
#define NN 30   // N
#define NT 50   // T
#define ND 4    // D
#define NK 4    // K experts
#define NE 870  // E = N*(N-1)

// canonical workspace layout (element offsets from ws+16, all %8==0 -> 16B aligned)
#define C_INPUTS   0        // 96000
#define C_RELTYPE  96000    // 55680
#define C_B1       151680   // 512
#define C_B2       152192   // 512
#define C_OB1      152704   // 128
#define C_OB2      152832   // 128
#define C_OW3      152960   // 512
#define C_OB3      153472   // 4 (pad to 8)
#define C_W1F      153480   // 16384  W1 fragments  [k][ct][quad][lm][j] (quad>0 zero)
#define C_W2F      169864   // 65536  W2 fragments  [k][kc][quad][ct][lm][j]
#define C_OW1F     235400   // 20480  oW1 fragments [ct][kc(5)][quad][lm][j] (kk>=132 zero)
#define C_OW2F     255880   // 16384  oW2 fragments [ct][kc(4)][quad][lm][j]
#define AGG_BYTE_OFF (1u << 20)   // aggbuf (fp32) at ws + 1MB

__device__ __forceinline__ bf16x8 bzero8() {
  bf16x8 z;
#pragma unroll
  for (int j = 0; j < 8; ++j) z[j] = (bf16_t)0.0f;
  return z;
}

__device__ __forceinline__ f32x4 make4(float a, float b, float c, float d) {
  f32x4 v; v[0] = a; v[1] = b; v[2] = c; v[3] = d; return v;
}

// relu + cvt to bf16 + packed 8B store (vector-typed: alias-safe)
__device__ __forceinline__ void pack_store4(bf16_t* dst, f32x4 a) {
  bf16x4 v;
  v[0] = (bf16_t)fmaxf(a[0], 0.0f);
  v[1] = (bf16_t)fmaxf(a[1], 0.0f);
  v[2] = (bf16_t)fmaxf(a[2], 0.0f);
  v[3] = (bf16_t)fmaxf(a[3], 0.0f);
  *(bf16x4*)dst = v;
}

// ---------------------------------------------------------------------------
// dtype detection + canonicalization (bf16) + weight fragment pre-permutation
// ---------------------------------------------------------------------------
__device__ __forceinline__ int detect_isbf16(const void* p) {
  const unsigned short* w = (const unsigned short*)p;
  int c = 0;
#pragma unroll 4
  for (int i = 0; i < 256; i += 2) {
    const int e = (w[i] >> 7) & 0xFF;
    if (e >= 100 && e <= 150) ++c;
  }
  return c >= 96;   // bf16 ~128/128, fp32 ~25/128
}

__device__ __forceinline__ float ldf(const void* src, int idx, int isbf) {
  return isbf ? (float)((const bf16_t*)src)[idx] : ((const float*)src)[idx];
}

__device__ __forceinline__ void conv_arr(const void* src, bf16_t* dst, int n,
                                         int isbf, int gtid, int gsz) {
  if (isbf) {
    const unsigned short* s = (const unsigned short*)src;
    unsigned short* d = (unsigned short*)dst;
    for (int i = gtid; i < n; i += gsz) d[i] = s[i];
  } else {
    const float* s = (const float*)src;
    for (int i = gtid; i < n; i += gsz) dst[i] = (bf16_t)s[i];
  }
}

__global__ void convert_kernel(const void* inputs, const void* rel_type,
                               const void* W1, const void* b1,
                               const void* W2, const void* b2,
                               const void* oW1, const void* ob1,
                               const void* oW2, const void* ob2,
                               const void* oW3, const void* ob3,
                               void* ws)
{
  __shared__ int sflag;
  if (threadIdx.x == 0) sflag = detect_isbf16(inputs);
  __syncthreads();
  const int isbf = sflag;
  if (blockIdx.x == 0 && threadIdx.x == 0) *(int*)ws = isbf;
  bf16_t* cb = (bf16_t*)((char*)ws + 16);
  const int gtid = blockIdx.x * blockDim.x + threadIdx.x;
  const int gsz  = gridDim.x * blockDim.x;

  conv_arr(inputs,   cb + C_INPUTS,  96000, isbf, gtid, gsz);
  conv_arr(rel_type, cb + C_RELTYPE, 55680, isbf, gtid, gsz);
  conv_arr(b1,  cb + C_B1,  512, isbf, gtid, gsz);
  conv_arr(b2,  cb + C_B2,  512, isbf, gtid, gsz);
  conv_arr(ob1, cb + C_OB1, 128, isbf, gtid, gsz);
  conv_arr(ob2, cb + C_OB2, 128, isbf, gtid, gsz);
  conv_arr(oW3, cb + C_OW3, 512, isbf, gtid, gsz);
  conv_arr(ob3, cb + C_OB3, 4,   isbf, gtid, gsz);

  // W1 fragments: idx = (((k*8+ct)*4+quad)*16+lm)*8+j ; quad>0 -> 0
  for (int i = gtid; i < 16384; i += gsz) {
    const int j = i & 7, lm = (i >> 3) & 15, quad = (i >> 7) & 3;
    const int ct = (i >> 9) & 7, k = (i >> 12) & 3;
    float v = 0.0f;
    if (quad == 0) v = ldf(W1, k * 1024 + j * 128 + ct * 16 + lm, isbf);
    cb[C_W1F + i] = (bf16_t)v;
  }
  // W2 fragments: idx = ((((k*4+kc)*4+quad)*8)+ct)*128 + lm*8 + j
  for (int i = gtid; i < 65536; i += gsz) {
    const int j = i & 7, lm = (i >> 3) & 15, ct = (i >> 7) & 7;
    const int quad = (i >> 10) & 3, kc = (i >> 12) & 3, k = (i >> 14) & 3;
    const int kk = kc * 32 + quad * 8 + j;
    cb[C_W2F + i] = (bf16_t)ldf(W2, k * 16384 + kk * 128 + ct * 16 + lm, isbf);
  }
  // oW1 fragments: idx = (((ct*5+kc)*4+quad)*16+lm)*8+j ; kk>=132 -> 0
  for (int i = gtid; i < 20480; i += gsz) {
    const int j = i & 7, lm = (i >> 3) & 15, quad = (i >> 7) & 3;
    const int rem = i >> 9;              // 0..39
    const int kc = rem % 5, ct = rem / 5;
    const int kk = kc * 32 + quad * 8 + j;
    float v = 0.0f;
    if (kk < 132) v = ldf(oW1, kk * 128 + ct * 16 + lm, isbf);
    cb[C_OW1F + i] = (bf16_t)v;
  }
  // oW2 fragments: idx = (((ct*4+kc)*4+quad)*16+lm)*8+j
  for (int i = gtid; i < 16384; i += gsz) {
    const int j = i & 7, lm = (i >> 3) & 15, quad = (i >> 7) & 3;
    const int kc = (i >> 9) & 3, ct = (i >> 11) & 7;
    const int kk = kc * 32 + quad * 8 + j;
    cb[C_OW2F + i] = (bf16_t)ldf(oW2, kk * 128 + ct * 16 + lm, isbf);
  }
}

// ---------------------------------------------------------------------------
// Edge kernel: per (b,t,half) block computes 15 receiver nodes (435 edges),
// all 4 experts. Weight fragments come pre-permuted from global (L2-hot) ->
// no LDS staging, no transposes, NO barriers inside the k/tile loops.
// ---------------------------------------------------------------------------
struct EdgeSmem {
  bf16_t h[64 * 136];      // 17408 B  layer-1 activations [edge][n] (wave-private rows)
  float  agg[16 * 128];    // 8192 B   (row 15 = scratch for the 1-node tile)
  float  rt4[436 * 4];     // 6976 B   rel_type slice, [edge_local][k]
  float  b1f4[512];        // 2048 B
  float  b2f4[512];        // 2048 B
  bf16_t xl[128];          // 256 B    x[b,t,:,:] (30 nodes x 4)
};                          // ~36.9 KB

__global__ __launch_bounds__(256, 2)
void edge_kernel(const bf16_t* __restrict__ inputs,
                 const bf16_t* __restrict__ rel_type,
                 const bf16_t* __restrict__ w1f_g,
                 const bf16_t* __restrict__ w2f_g,
                 const bf16_t* __restrict__ b1,
                 const bf16_t* __restrict__ b2,
                 float* __restrict__ aggbuf)
{
  __shared__ EdgeSmem s;
  const int tid  = threadIdx.x;
  const int bid  = blockIdx.x;
  const int nhalf = bid & 1;
  const int bt   = bid >> 1;
  const int b    = bt / NT;
  const int t    = bt - b * NT;
  const int wave = tid >> 6;
  const int lane = tid & 63;
  const int quad = lane >> 4;
  const int lm   = lane & 15;
  const int rowm = wave * 16 + lm;

  // ---- one-time staging (single barrier) ----
  if (tid < 30) {
    *(uint2*)&s.xl[tid * 4] = *(const uint2*)&inputs[((b * NN + tid) * NT + t) * ND];
  }
  for (int i = tid; i < 512; i += 256) {
    s.b1f4[i] = (float)b1[i];
    s.b2f4[i] = (float)b2[i];
  }
  {
    const int e0g = b * NE + nhalf * 435;
    for (int i = tid; i < 435; i += 256) {
      union { uint2 u2; bf16_t h[4]; } c;
      c.u2 = *(const uint2*)&rel_type[(e0g + i) * NK];
#pragma unroll
      for (int kk = 0; kk < 4; ++kk) s.rt4[i * 4 + kk] = (float)c.h[kk];
    }
  }
  for (int i = tid; i < 16 * 128; i += 256) s.agg[i] = 0.0f;
  __syncthreads();

  for (int k = 0; k < NK; ++k) {
    // ---- coalesced fragment loads, global -> registers (L2-hot) ----
    bf16x8 w2r[8][4];
    bf16x8 w1r[8];
#pragma unroll
    for (int ct = 0; ct < 8; ++ct) {
#pragma unroll
      for (int kc = 0; kc < 4; ++kc)
        w2r[ct][kc] = *(const bf16x8*)&w2f_g[((((k * 4 + kc) * 4 + quad) * 8) + ct) * 128 + lm * 8];
      w1r[ct] = *(const bf16x8*)&w1f_g[(((k * 8 + ct) * 4 + quad) * 16 + lm) * 8];
    }
    f32x4 b1v[8];
    float b2s[8];
#pragma unroll
    for (int ct = 0; ct < 8; ++ct) {
      const int nb = ct * 16 + quad * 4;
      b1v[ct] = make4(s.b1f4[k * 128 + nb],     s.b1f4[k * 128 + nb + 1],
                      s.b1f4[k * 128 + nb + 2], s.b1f4[k * 128 + nb + 3]);
      b2s[ct] = s.b2f4[k * 128 + ct * 16 + lm];
    }

    // ---- 8 tiles of 2 nodes (58 edges, padded to 64); tile 7 has 1 node ----
    for (int tt = 0; tt < 8; ++tt) {
      const int vcnt = (tt < 7) ? 58 : 29;
      const int n0g  = nhalf * 15 + tt * 2;

      float rtv[4];
      bool  seg1[4];
#pragma unroll
      for (int r = 0; r < 4; ++r) {
        const int rr = wave * 16 + quad * 4 + r;
        rtv[r]  = (rr < vcnt) ? s.rt4[(tt * 58 + rr) * 4 + k] : 0.0f;
        seg1[r] = (rr >= 29);
      }

      // premsg B-fragment: [x_recv(4), x_send(4)] at k=0..7, zero elsewhere
      bf16x8 pm = bzero8();
      if (quad == 0 && rowm < vcnt) {
        const int recv = n0g + (rowm >= 29);
        const int jj   = rowm - ((rowm >= 29) ? 29 : 0);
        const int send = jj + ((jj >= recv) ? 1 : 0);
        union { uint2 u2[2]; bf16x8 v; } c;
        c.u2[0] = *(const uint2*)&s.xl[recv * 4];
        c.u2[1] = *(const uint2*)&s.xl[send * 4];
        pm = c.v;
      }

      // layer 1 (operand-swapped): D'[n][edge]; packed b64 stores to h[edge][n]
#pragma unroll
      for (int ct = 0; ct < 8; ++ct) {
        f32x4 a1 = __builtin_amdgcn_mfma_f32_16x16x32_bf16(w1r[ct], pm, b1v[ct], 0, 0, 0);
        pack_store4(&s.h[rowm * 136 + ct * 16 + quad * 4], a1);
      }

      // layer 2 (un-swapped): D[edge][m], bias in C-init
      f32x4 acc2[8];
#pragma unroll
      for (int ct = 0; ct < 8; ++ct)
        acc2[ct] = make4(b2s[ct], b2s[ct], b2s[ct], b2s[ct]);
#pragma unroll
      for (int kc = 0; kc < 4; ++kc) {
        const bf16x8 af = *(const bf16x8*)&s.h[rowm * 136 + kc * 32 + quad * 8];
#pragma unroll
        for (int ct = 0; ct < 8; ++ct)
          acc2[ct] = __builtin_amdgcn_mfma_f32_16x16x32_bf16(af, w2r[ct][kc], acc2[ct], 0, 0, 0);
      }

      // relu * rt, segmented reduce over 16 edges (4 regs + quad butterfly)
#pragma unroll
      for (int ct = 0; ct < 8; ++ct) {
        float p0 = 0.0f, p1 = 0.0f;
#pragma unroll
        for (int r = 0; r < 4; ++r) {
          const float v = fmaxf(acc2[ct][r], 0.0f) * rtv[r];
          p0 += seg1[r] ? 0.0f : v;
          p1 += seg1[r] ? v : 0.0f;
        }
        p0 += __shfl_xor(p0, 16, 64);
        p0 += __shfl_xor(p0, 32, 64);
        p1 += __shfl_xor(p1, 16, 64);
        p1 += __shfl_xor(p1, 32, 64);
        if (quad == 0) {
          const int col = ct * 16 + lm;
          atomicAdd(&s.agg[(tt * 2) * 128 + col], p0);
          atomicAdd(&s.agg[(tt * 2 + 1) * 128 + col], p1);
        }
      }
    }
  }

  __syncthreads();
  for (int i = tid; i < 15 * 128; i += 256) {
    const int r = i >> 7, c = i & 127;
    aggbuf[(size_t)(bt * NN + nhalf * 15 + r) * 128 + c] = s.agg[r * 128 + c];
  }
}

// ---------------------------------------------------------------------------
// Node kernel: 64 node-instances per block; aug = [x(4), agg(128), 0-pad]
// Fragment weights from global; h1/h2 wave-private -> single initial barrier.
// ---------------------------------------------------------------------------
struct NodeSmem {
  bf16_t h1[64 * 136];     // 17408 B
  bf16_t h2[64 * 136];     // 17408 B
  bf16_t xres[64 * 4];
  float  b1f[128];
  float  b2f[128];
  float  w3f[128 * 4];
  float  b3f[4];
};                          // ~38.4 KB

__global__ __launch_bounds__(256, 2)
void node_kernel(const bf16_t* __restrict__ inputs,
                 const bf16_t* __restrict__ ow1f_g, const bf16_t* __restrict__ ob1,
                 const bf16_t* __restrict__ ow2f_g, const bf16_t* __restrict__ ob2,
                 const bf16_t* __restrict__ oW3, const bf16_t* __restrict__ ob3,
                 const int* __restrict__ flagptr,
                 const float* __restrict__ aggbuf,
                 void* __restrict__ outp)
{
  __shared__ NodeSmem s;
  const int tid  = threadIdx.x;
  const int wave = tid >> 6;
  const int lane = tid & 63;
  const int quad = lane >> 4;
  const int lm   = lane & 15;
  const int row  = wave * 16 + lm;
  const int r0   = blockIdx.x * 64;
  const int isbf = *flagptr;

  // ---- one-time staging (single barrier) ----
  if (tid < 64) {
    const int r  = r0 + tid;
    const int n  = r % NN;
    const int bt = r / NN;
    const int t  = bt % NT;
    const int b  = bt / NT;
    *(uint2*)&s.xres[tid * 4] = *(const uint2*)&inputs[((b * NN + n) * NT + t) * ND];
  }
  if (tid < 128) s.b1f[tid] = (float)ob1[tid];
  else           s.b2f[tid - 128] = (float)ob2[tid - 128];
  if (tid < 4) s.b3f[tid] = (float)ob3[tid];
  for (int i = tid; i < 512; i += 256) s.w3f[i] = (float)oW3[i];
  __syncthreads();

  // ---- oW1 fragments (zeros for kk>=132 baked in) ----
  bf16x8 wf1[8][5];
#pragma unroll
  for (int ct = 0; ct < 8; ++ct)
#pragma unroll
    for (int kc = 0; kc < 5; ++kc)
      wf1[ct][kc] = *(const bf16x8*)&ow1f_g[(((ct * 5 + kc) * 4 + quad) * 16 + lm) * 8];

  // ---- build aug B-fragments directly from global agg (fp32) + x ----
  bf16x8 bfa[5];
  {
    const float* aggrow = aggbuf + (size_t)(r0 + row) * 128;
    float tmp[8];
    if (quad == 0) {
#pragma unroll
      for (int j = 0; j < 4; ++j) tmp[j] = (float)s.xres[row * 4 + j];
      const float4 a = *(const float4*)(aggrow);
      tmp[4] = a.x; tmp[5] = a.y; tmp[6] = a.z; tmp[7] = a.w;
    } else {
      const int c0 = quad * 8 - 4;
      const float4 a = *(const float4*)(aggrow + c0);
      const float4 d = *(const float4*)(aggrow + c0 + 4);
      tmp[0] = a.x; tmp[1] = a.y; tmp[2] = a.z; tmp[3] = a.w;
      tmp[4] = d.x; tmp[5] = d.y; tmp[6] = d.z; tmp[7] = d.w;
    }
#pragma unroll
    for (int j = 0; j < 8; ++j) bfa[0][j] = (bf16_t)tmp[j];
#pragma unroll
    for (int kc = 1; kc < 4; ++kc) {
      const int c0 = kc * 32 + quad * 8 - 4;
      const float4 a = *(const float4*)(aggrow + c0);
      const float4 d = *(const float4*)(aggrow + c0 + 4);
      tmp[0] = a.x; tmp[1] = a.y; tmp[2] = a.z; tmp[3] = a.w;
      tmp[4] = d.x; tmp[5] = d.y; tmp[6] = d.z; tmp[7] = d.w;
#pragma unroll
      for (int j = 0; j < 8; ++j) bfa[kc][j] = (bf16_t)tmp[j];
    }
    if (quad == 0) {
      const float4 a = *(const float4*)(aggrow + 124);
      tmp[0] = a.x; tmp[1] = a.y; tmp[2] = a.z; tmp[3] = a.w;
      tmp[4] = 0.f; tmp[5] = 0.f; tmp[6] = 0.f; tmp[7] = 0.f;
#pragma unroll
      for (int j = 0; j < 8; ++j) bfa[4][j] = (bf16_t)tmp[j];
    } else bfa[4] = bzero8();
  }

  // ---- layer 1 (swapped): h1[row][n] ----
  {
    f32x4 acc[8];
#pragma unroll
    for (int ct = 0; ct < 8; ++ct) {
      const int nb = ct * 16 + quad * 4;
      acc[ct] = make4(s.b1f[nb], s.b1f[nb + 1], s.b1f[nb + 2], s.b1f[nb + 3]);
    }
#pragma unroll
    for (int kc = 0; kc < 5; ++kc) {
#pragma unroll
      for (int ct = 0; ct < 8; ++ct)
        acc[ct] = __builtin_amdgcn_mfma_f32_16x16x32_bf16(wf1[ct][kc], bfa[kc], acc[ct], 0, 0, 0);
    }
#pragma unroll
    for (int ct = 0; ct < 8; ++ct)
      pack_store4(&s.h1[row * 136 + ct * 16 + quad * 4], acc[ct]);
  }
  // no barrier: h1 rows are wave-private

  // ---- oW2 fragments ----
  bf16x8 wf2[8][4];
#pragma unroll
  for (int ct = 0; ct < 8; ++ct)
#pragma unroll
    for (int kc = 0; kc < 4; ++kc)
      wf2[ct][kc] = *(const bf16x8*)&ow2f_g[(((ct * 4 + kc) * 4 + quad) * 16 + lm) * 8];

  // ---- layer 2 (swapped): h2[row][m] ----
  {
    f32x4 acc[8];
#pragma unroll
    for (int ct = 0; ct < 8; ++ct) {
      const int mb = ct * 16 + quad * 4;
      acc[ct] = make4(s.b2f[mb], s.b2f[mb + 1], s.b2f[mb + 2], s.b2f[mb + 3]);
    }
#pragma unroll
    for (int kc = 0; kc < 4; ++kc) {
      const bf16x8 af = *(const bf16x8*)&s.h1[row * 136 + kc * 32 + quad * 8];
#pragma unroll
      for (int ct = 0; ct < 8; ++ct)
        acc[ct] = __builtin_amdgcn_mfma_f32_16x16x32_bf16(wf2[ct][kc], af, acc[ct], 0, 0, 0);
    }
#pragma unroll
    for (int ct = 0; ct < 8; ++ct)
      pack_store4(&s.h2[row * 136 + ct * 16 + quad * 4], acc[ct]);
  }
  // no barrier: h2 rows are wave-private and layer-3 lanes read own wave's rows

  // ---- layer 3 (VALU) + residual + store ----
  {
    const int rloc = tid >> 2;
    const int d    = tid & 3;
    float a3 = s.b3f[d];
#pragma unroll
    for (int g = 0; g < 16; ++g) {
      const bf16x8 hv = *(const bf16x8*)&s.h2[rloc * 136 + g * 8];
#pragma unroll
      for (int j = 0; j < 8; ++j)
        a3 += (float)hv[j] * s.w3f[(g * 8 + j) * 4 + d];
    }
    a3 += (float)s.xres[rloc * 4 + d];
    const int r  = r0 + rloc;
    const int n  = r % NN;
    const int bt = r / NN;
    const int t  = bt % NT;
    const int b  = bt / NT;
    if (t < NT - 1) {
      const int oidx = ((b * NN + n) * (NT - 1) + t) * ND + d;
      if (isbf) ((bf16_t*)outp)[oidx] = (bf16_t)a3;
      else      ((float*)outp)[oidx]  = a3;
    }
  }
}

extern "C" void kernel_launch(void* const* d_in, const int* in_sizes, int n_in,
                              void* d_out, int out_size, void* d_ws, size_t ws_size,
                              hipStream_t stream) {
  // d_in[2] rel_rec, d_in[3] rel_send: fixed one-hot structure, computed
  // analytically. d_in[14] pred_steps == 1.
  char* ws = (char*)d_ws;
  bf16_t* cb = (bf16_t*)(ws + 16);             // canonical bf16 arrays + fragments
  float* aggbuf = (float*)(ws + AGG_BYTE_OFF); // 24000*128*4 B = 12.29 MB

  convert_kernel<<<dim3(256), dim3(256), 0, stream>>>(
      d_in[0], d_in[1], d_in[4], d_in[5], d_in[6], d_in[7],
      d_in[8], d_in[9], d_in[10], d_in[11], d_in[12], d_in[13], d_ws);

  edge_kernel<<<dim3(NB * NT * 2), dim3(256), 0, stream>>>(
      cb + C_INPUTS, cb + C_RELTYPE, cb + C_W1F, cb + C_W2F,
      cb + C_B1, cb + C_B2, aggbuf);

  node_kernel<<<dim3((NB * NT * NN) / 64), dim3(256), 0, stream>>>(
      cb + C_INPUTS, cb + C_OW1F, cb + C_OB1, cb + C_OW2F, cb + C_OB2,
      cb + C_OW3, cb + C_OB3, (const int*)d_ws, aggbuf, d_out);
}